// Round 13
// baseline (312.202 us; speedup 1.0000x reference)
//
#include <hip/hip_runtime.h>

#define NB 64        // bins
#define HW 65536     // pixels per channel (256*256)
#define NCH 24       // B*C = 8*3
#define SPLIT 8      // segments per channel-image
#define NPAIR 38     // 76 slots as 38 float2 pairs; slot = bin + 6, bins -6..69

// w_j(x) = exp(-K*(f-j)^2), f = 63x, K = 2048/3969.
// Even-aligned 12-tap window: e0 = (rint(f)-5) & ~1, c0 = e0+6,
// d' = f - c0 in [-1.5, 0.5]; taps r = -6..5 -> bins e0..e0+11 (superset of
// the +-5 window; dropped mass < 1.5e-7 relative). 3 transcendentals, 12 taps.
//
// r13 change (single variable vs r9): the 6 ds_read_b64 + 6 ds_write_b64
// RMW becomes 12 ds_add_f32 to PRIVATE per-thread columns.
// Rationale (r12 marginal-cost probe): hist ~= 15us FIXED latency + 8us
// throughput — the fixed part is the per-pixel read->wait->write chain that
// 2 waves/SIMD can't hide (why r3/r8/r10/r11 levers were all null: they cut
// throughput, not latency). ds_add_f32 is fire-and-forget: no result, no
// lgkmcnt wait, no VGPR round-trip -> the chain collapses to ladder+issue.
// NOT r1's config: r1 had 4 waves x same-address contention on shared
// columns. Here every address belongs to ONE thread: zero contention,
// zero races. Banks: (2*tid+e)%32, pair stride 2048B == 0 mod 32 banks ->
// uniform 2-way (free). Init/fold/tail identical to r9 (best, 72.3us).
__global__ __launch_bounds__(256) void chml_hist(const float* __restrict__ pred,
                                                 const float* __restrict__ targ,
                                                 float* __restrict__ part,
                                                 float* __restrict__ out) {
  const int seg = blockIdx.x;   // 0..SPLIT-1
  const int ct  = blockIdx.y;   // 0..2*NCH-1
  const float* src = (ct < NCH) ? (pred + (size_t)ct * HW)
                                : (targ + (size_t)(ct - NCH) * HW);
  const int tid = threadIdx.x;

  if (seg == 0 && ct == 0 && tid == 0) out[0] = 0.0f;  // for chan's atomicAdd

  // issue all 8 global float4 loads first (in flight during LDS init)
  const float4* s4 = (const float4*)(src + (size_t)seg * (HW / SPLIT));
  float4 P[8];
#pragma unroll
  for (int i = 0; i < 8; ++i) P[i] = s4[i * 256 + tid];

  __shared__ float2 H[NPAIR][256];   // 77824 B -> 2 blocks/CU
  {
    float4* hz = (float4*)&H[0][0];
#pragma unroll
    for (int i = tid; i < NPAIR * 256 * 2 / 4; i += 256)
      hz[i] = make_float4(0.f, 0.f, 0.f, 0.f);
  }
  __syncthreads();

  const float K  = 0.51599899f;      // 2048/3969
  const float C1 = 5.96905619e-01f;  // exp(-K*1)
  const float C2 = 1.26927917e-01f;  // exp(-K*4)
  const float C3 = 9.61165782e-03f;  // exp(-K*9)
  const float C4 = 2.59240329e-04f;  // exp(-K*16)
  const float C5 = 2.49029640e-06f;  // exp(-K*25)
  const float C6 = 8.56260000e-09f;  // exp(-K*36)

  // float-addressed private column base: floats {2*tid, 2*tid+1} of each pair
  float* const hb = (float*)&H[0][0] + 2 * tid;   // pair stride = 512 floats

#pragma unroll
  for (int k2 = 0; k2 < 8; ++k2) {
    float4 p = P[k2];
    float pe[4] = {p.x, p.y, p.z, p.w};
#pragma unroll
    for (int e = 0; e < 4; ++e) {
      float f  = pe[e] * 63.0f;
      float n  = rintf(f);
      int   ni = (int)n;                        // 0..63
      int   e0 = (ni - 5) & ~1;                 // even, in [-6, 58]
      float dp = f - (float)(e0 + 6);           // d' in [-1.5, 0.5]
      float* tp = hb + (((e0 >> 1) + 3) << 9);  // pair p0 = (e0+6)/2, *512 floats
      // ---- weight ladder
      float w0 = __expf(dp * dp * -K);
      float mp = __expf(dp * (2.0f * K));
      float mn = __expf(dp * (-2.0f * K));
      float mp2 = mp * mp, mp3 = mp2 * mp, mp4 = mp2 * mp2, mp5 = mp4 * mp;
      float mn2 = mn * mn, mn3 = mn2 * mn, mn4 = mn2 * mn2, mn5 = mn4 * mn,
            mn6 = mn3 * mn3;
      float A1 = w0 * C1, A2 = w0 * C2, A3 = w0 * C3, A4 = w0 * C4,
            A5 = w0 * C5, A6 = w0 * C6;
      // ---- 12 fire-and-forget private LDS adds (ds_add_f32, imm offsets)
      atomicAdd(&tp[0 * 512 + 0], A6 * mn6);   // r = -6
      atomicAdd(&tp[0 * 512 + 1], A5 * mn5);   // r = -5
      atomicAdd(&tp[1 * 512 + 0], A4 * mn4);
      atomicAdd(&tp[1 * 512 + 1], A3 * mn3);
      atomicAdd(&tp[2 * 512 + 0], A2 * mn2);
      atomicAdd(&tp[2 * 512 + 1], A1 * mn);
      atomicAdd(&tp[3 * 512 + 0], w0);         // r = 0
      atomicAdd(&tp[3 * 512 + 1], A1 * mp);
      atomicAdd(&tp[4 * 512 + 0], A2 * mp2);
      atomicAdd(&tp[4 * 512 + 1], A3 * mp3);
      atomicAdd(&tp[5 * 512 + 0], A4 * mp4);
      atomicAdd(&tp[5 * 512 + 1], A5 * mp5);   // r = +5
    }
  }
  __syncthreads();

  // Fold 256 columns -> 1 per pair. Lane l (<38) owns pair l; wave wv sums
  // rows [64wv, 64wv+64) with staggered row order (i+l)&63 -> uniform b64
  // banks, conflict-free.
  const int wv = tid >> 6, l = tid & 63;
  float2 facc = make_float2(0.f, 0.f);
  if (l < NPAIR) {
    const float2* col = &H[l][wv << 6];
#pragma unroll 8
    for (int i = 0; i < 64; ++i) {
      float2 v = col[(i + l) & 63];
      facc.x += v.x; facc.y += v.y;
    }
  }
  __syncthreads();
  if (l < NPAIR) H[l][wv] = facc;   // scratch: rows 0..3 (already consumed)
  __syncthreads();
  if (tid < NPAIR) {
    float2 a = H[tid][0], b2 = H[tid][1], c2 = H[tid][2], d2 = H[tid][3];
    float sx = a.x + b2.x + c2.x + d2.x;
    float sy = a.y + b2.y + c2.y + d2.y;
    int bin0 = 2 * tid - 6;          // slot 2*tid -> bin = slot - 6
    float* dst = part + ((size_t)ct * SPLIT + seg) * NB;
    if (bin0 >= 0 && bin0 < NB) dst[bin0] = sx;
    int bin1 = bin0 + 1;
    if (bin1 >= 0 && bin1 < NB) dst[bin1] = sy;
  }
}

// Merged tail: per-channel CDF loss, pre-scaled atomicAdd into out.
// 24 blocks x 64 threads (parallel across CUs — r5 lesson). out was zeroed
// by hist block (0,0); stream order makes this race-free.
__global__ __launch_bounds__(64) void chml_chan(const float* __restrict__ part,
                                                float* __restrict__ out) {
  const int c    = blockIdx.x;
  const int lane = threadIdx.x;
  float vp = 0.0f, vt = 0.0f;
#pragma unroll
  for (int s = 0; s < SPLIT; ++s) {
    vp += part[((size_t)c * SPLIT + s) * NB + lane];
    vt += part[((size_t)(c + NCH) * SPLIT + s) * NB + lane];
  }
  // inclusive prefix scan across 64 lanes
#pragma unroll
  for (int off = 1; off < 64; off <<= 1) {
    float up = __shfl_up(vp, off, 64);
    float ut = __shfl_up(vt, off, 64);
    if (lane >= off) { vp += up; vt += ut; }
  }
  float totp = __shfl(vp, 63, 64);
  float tott = __shfl(vt, 63, 64);
  float l = fabsf(vp / (totp + 1e-7f) - vt / (tott + 1e-7f));
#pragma unroll
  for (int off = 32; off >= 1; off >>= 1) l += __shfl_xor(l, off, 64);
  if (lane == 0) atomicAdd(out, l * (1.0f / (float)(NCH * NB)));
}

extern "C" void kernel_launch(void* const* d_in, const int* in_sizes, int n_in,
                              void* d_out, int out_size, void* d_ws, size_t ws_size,
                              hipStream_t stream) {
  const float* pred = (const float*)d_in[0];
  const float* targ = (const float*)d_in[1];
  float* part = (float*)d_ws;        // 48*8*64 floats = 96 KB

  dim3 grid(SPLIT, 2 * NCH);
  chml_hist<<<grid, 256, 0, stream>>>(pred, targ, part, (float*)d_out);
  chml_chan<<<NCH, 64, 0, stream>>>(part, (float*)d_out);
}

// Round 14
// 72.317 us; speedup vs baseline: 4.3172x; 4.3172x over previous
//
#include <hip/hip_runtime.h>

#define NB 64        // bins
#define HW 65536     // pixels per channel (256*256)
#define NCH 24       // B*C = 8*3
#define SPLIT 16     // segments per channel-image
#define NSLOT 76     // slots = bin + 6, bins -6..69

typedef __attribute__((ext_vector_type(2))) float f32x2;

// w_j(x) = exp(-K*(f-j)^2), f = 63x, K = 2048/3969.
// Even-aligned 12-tap window: e0 = (rint(f)-5) & ~1, taps at slots
// s = e0+6+k, k=0..11 (bins e0..e0+11; dropped mass < 1.5e-7).
//
// r14 structure: PARITY-SPLIT COLUMNS to double occupancy (attack the F~15us
// fixed-latency term from the r12 decomposition; T-levers were all null).
// float H[76][128]: thread pair (t, t+128) shares column c = t&127.
//   t (p=0, waves 0-1):  even k -> r in {-6,-4,-2,0,2,4}
//   t+128 (p=1, waves 2-3): odd k -> r in {-5,-3,-1,1,3,5}
// Disjoint addresses -> no races (NO atomics: r13 proved ds_add ~200cy).
// Both threads process the same 32 pixels (ladder recomputed: VALU ~5% busy,
// free; parity is wave-uniform -> no divergence).
// LDS 76*128*4 = 38912 B -> 4 blocks/CU (vs 2): 3-4 waves/SIMD at SPLIT=16.
// DS instrs per thread UNCHANGED vs r9: 32 px x (3 ds_read2st64_b32 +
// 3 ds_write2st64_b32); tap stride = 2 slots = 1024 B = 4 st64 units ->
// offsets 0,4/8,12/16,20 (r11-proven pattern, absmax 0.0).
// Banks stay deterministic: addr = slot*512B + c*4B, 512 == 0 mod 32 banks
// -> bank = c%32 uniform 2-way (the random slot lands in the bank-invariant
// stride — r9's trick preserved).
__global__ __launch_bounds__(256) void chml_hist(const float* __restrict__ pred,
                                                 const float* __restrict__ targ,
                                                 float* __restrict__ part,
                                                 float* __restrict__ out) {
  const int seg = blockIdx.x;   // 0..SPLIT-1
  const int ct  = blockIdx.y;   // 0..2*NCH-1
  const float* src = (ct < NCH) ? (pred + (size_t)ct * HW)
                                : (targ + (size_t)(ct - NCH) * HW);
  const int tid = threadIdx.x;
  const int c   = tid & 127;    // column
  const int p   = tid >> 7;     // parity (wave-uniform)

  if (seg == 0 && ct == 0 && tid == 0) out[0] = 0.0f;  // for chan's atomicAdd

  // column c owns contiguous pixels [c*32, c*32+32) of the 4096-px segment;
  // both parity threads load the same 8 float4 (L1/L2-absorbed duplicate).
  const float4* s4 = (const float4*)(src + (size_t)seg * (HW / SPLIT));
  float4 P[8];
#pragma unroll
  for (int i = 0; i < 8; ++i) P[i] = s4[c * 8 + i];

  __shared__ float H[NSLOT][128];   // 38912 B -> 4 blocks/CU
  {
    float4* hz = (float4*)&H[0][0];
    for (int i = tid; i < NSLOT * 128 / 4; i += 256)
      hz[i] = make_float4(0.f, 0.f, 0.f, 0.f);
  }
  __syncthreads();

  const float K  = 0.51599899f;      // 2048/3969
  const float C1 = 5.96905619e-01f;  // exp(-K*1)
  const float C2 = 1.26927917e-01f;  // exp(-K*4)
  const float C3 = 9.61165782e-03f;  // exp(-K*9)
  const float C4 = 2.59240329e-04f;  // exp(-K*16)
  const float C5 = 2.49029640e-06f;  // exp(-K*25)
  const float C6 = 8.56260000e-09f;  // exp(-K*36)

  // LDS byte offset of this thread's column base (+ parity slot offset).
  typedef __attribute__((address_space(3))) float lds_f32;
  const unsigned hbase =
      (unsigned)(size_t)((lds_f32*)&H[0][0] + c) + ((unsigned)p << 9);

#pragma unroll
  for (int k2 = 0; k2 < 8; ++k2) {
    float4 p4 = P[k2];
    float pe[4] = {p4.x, p4.y, p4.z, p4.w};
#pragma unroll
    for (int e = 0; e < 4; ++e) {
      float f  = pe[e] * 63.0f;
      float n  = rintf(f);
      int   ni = (int)n;                        // 0..63
      int   e0 = (ni - 5) & ~1;                 // even, in [-6, 58]
      float dp = f - (float)(e0 + 6);           // d' in [-1.5, 0.5]
      // slot s0 = e0+6(+p) ; addr = hbase + (e0+6)*512 (p folded into hbase)
      unsigned a = hbase + ((unsigned)(e0 + 6) << 9);
      // ---- 3 dual reads: taps (0,2),(4,6),(8,10)+p slots rel. e0+6
      f32x2 t01, t23, t45;
      asm volatile("ds_read2st64_b32 %0, %1 offset0:0 offset1:4"
                   : "=v"(t01) : "v"(a));
      asm volatile("ds_read2st64_b32 %0, %1 offset0:8 offset1:12"
                   : "=v"(t23) : "v"(a));
      asm volatile("ds_read2st64_b32 %0, %1 offset0:16 offset1:20"
                   : "=v"(t45) : "v"(a));
      // ---- weight ladder (overlaps read latency)
      float w0 = __expf(dp * dp * -K);
      float mp = __expf(dp * (2.0f * K));
      float mn = __expf(dp * (-2.0f * K));
      float mp2 = mp * mp, mp3 = mp2 * mp, mp4 = mp2 * mp2, mp5 = mp4 * mp;
      float mn2 = mn * mn, mn3 = mn2 * mn, mn4 = mn2 * mn2, mn5 = mn4 * mn,
            mn6 = mn3 * mn3;
      float W0, W1, W2, W3, W4, W5;
      if (p == 0) {               // wave-uniform: even k -> r=-6,-4,-2,0,2,4
        W0 = w0 * (C6 * mn6); W1 = w0 * (C4 * mn4); W2 = w0 * (C2 * mn2);
        W3 = w0;              W4 = w0 * (C2 * mp2); W5 = w0 * (C4 * mp4);
      } else {                    // odd k -> r=-5,-3,-1,1,3,5
        W0 = w0 * (C5 * mn5); W1 = w0 * (C3 * mn3); W2 = w0 * (C1 * mn);
        W3 = w0 * (C1 * mp);  W4 = w0 * (C3 * mp3); W5 = w0 * (C5 * mp5);
      }
      // ---- drain reads (pass-through keeps adds ordered; rule #18)
      asm volatile("s_waitcnt lgkmcnt(0)"
                   : "+v"(t01), "+v"(t23), "+v"(t45));
      __builtin_amdgcn_sched_barrier(0);
      float d0 = t01.x + W0, d1 = t01.y + W1;
      float d2 = t23.x + W2, d3 = t23.y + W3;
      float d4 = t45.x + W4, d5 = t45.y + W5;
      // ---- 3 dual writes
      asm volatile("ds_write2st64_b32 %2, %0, %1 offset0:0 offset1:4"
                   :: "v"(d0), "v"(d1), "v"(a) : "memory");
      asm volatile("ds_write2st64_b32 %2, %0, %1 offset0:8 offset1:12"
                   :: "v"(d2), "v"(d3), "v"(a) : "memory");
      asm volatile("ds_write2st64_b32 %2, %0, %1 offset0:16 offset1:20"
                   :: "v"(d4), "v"(d5), "v"(a) : "memory");
    }
  }
  __syncthreads();

  // Fold: thread s (<76) sums its slot over 128 cols, b128 x 32 staggered
  // by s -> banks (4*((i+s)&31)+j)%32 spread across lanes, ~2-way.
  if (tid < NSLOT) {
    const int s = tid;
    float acc = 0.f;
#pragma unroll 8
    for (int i = 0; i < 32; ++i) {
      float4 v = *(const float4*)&H[s][4 * ((i + s) & 31)];
      acc += (v.x + v.y) + (v.z + v.w);
    }
    int bin = s - 6;
    if (bin >= 0 && bin < NB)
      part[((size_t)ct * SPLIT + seg) * NB + bin] = acc;
  }
}

// Merged tail: per-channel CDF loss, pre-scaled atomicAdd into out.
// 24 blocks x 64 threads (parallel across CUs — r5 lesson). out was zeroed
// by hist block (0,0); stream order makes this race-free.
__global__ __launch_bounds__(64) void chml_chan(const float* __restrict__ part,
                                                float* __restrict__ out) {
  const int c    = blockIdx.x;
  const int lane = threadIdx.x;
  float vp = 0.0f, vt = 0.0f;
#pragma unroll
  for (int s = 0; s < SPLIT; ++s) {
    vp += part[((size_t)c * SPLIT + s) * NB + lane];
    vt += part[((size_t)(c + NCH) * SPLIT + s) * NB + lane];
  }
  // inclusive prefix scan across 64 lanes
#pragma unroll
  for (int off = 1; off < 64; off <<= 1) {
    float up = __shfl_up(vp, off, 64);
    float ut = __shfl_up(vt, off, 64);
    if (lane >= off) { vp += up; vt += ut; }
  }
  float totp = __shfl(vp, 63, 64);
  float tott = __shfl(vt, 63, 64);
  float l = fabsf(vp / (totp + 1e-7f) - vt / (tott + 1e-7f));
#pragma unroll
  for (int off = 32; off >= 1; off >>= 1) l += __shfl_xor(l, off, 64);
  if (lane == 0) atomicAdd(out, l * (1.0f / (float)(NCH * NB)));
}

extern "C" void kernel_launch(void* const* d_in, const int* in_sizes, int n_in,
                              void* d_out, int out_size, void* d_ws, size_t ws_size,
                              hipStream_t stream) {
  const float* pred = (const float*)d_in[0];
  const float* targ = (const float*)d_in[1];
  float* part = (float*)d_ws;        // 48*16*64 floats = 196 KB

  dim3 grid(SPLIT, 2 * NCH);
  chml_hist<<<grid, 256, 0, stream>>>(pred, targ, part, (float*)d_out);
  chml_chan<<<NCH, 64, 0, stream>>>(part, (float*)d_out);
}